// Round 2
// baseline (89.396 us; speedup 1.0000x reference)
//
#include <hip/hip_runtime.h>
#include <math.h>

// x: (B=256, N=1024, D=256) fp32.  out = softmax(x[b,0,:] @ x[b]^T / 16) @ x[b] -> (256,1,256)
constexpr int BATCH = 256;
constexpr int N = 1024;
constexpr int D = 256;
constexpr int WAVES = 16;                     // 1024 threads / 64
constexpr int THREADS = WAVES * 64;
constexpr int SPLIT = 2;                      // blocks per batch -> 2 blocks/CU = 32 waves/CU
constexpr int KEYS_PER_BLOCK = N / SPLIT;     // 512
constexpr int KEYS_PER_WAVE = KEYS_PER_BLOCK / WAVES; // 32
constexpr int CHUNK = 2;
constexpr int NCHUNK = KEYS_PER_WAVE / CHUNK; // 16
constexpr int WS_STRIDE = D + 2;              // o[256], m, l

__global__ __launch_bounds__(THREADS, 8)
void attn_q0_partial(const float* __restrict__ x, float* __restrict__ ws) {
    const int b    = blockIdx.x >> 1;
    const int seg  = blockIdx.x & 1;
    const int tid  = threadIdx.x;
    const int wave = tid >> 6;
    const int lane = tid & 63;

    const float* __restrict__ xb = x + (size_t)b * (N * D);

    // q fragment: lane i holds q[4i..4i+3] (row 0; L1-broadcast across waves)
    const float4 q4 = *reinterpret_cast<const float4*>(xb + lane * 4);

    // this wave's contiguous 32-key span (32 KB linear stream)
    const float* __restrict__ base =
        xb + (size_t)(seg * KEYS_PER_BLOCK + wave * KEYS_PER_WAVE) * D + lane * 4;

    float  m_run = -INFINITY;
    float  l_run = 0.f;
    float4 o4    = make_float4(0.f, 0.f, 0.f, 0.f);

    float4 v[CHUNK];
#pragma unroll
    for (int j = 0; j < CHUNK; ++j)
        v[j] = *reinterpret_cast<const float4*>(base + j * D);

    for (int c = 0; c < NCHUNK; ++c) {
        float4 vn[CHUNK];
        const bool more = (c + 1 < NCHUNK);
        if (more) {
#pragma unroll
            for (int j = 0; j < CHUNK; ++j)
                vn[j] = *reinterpret_cast<const float4*>(base + ((c + 1) * CHUNK + j) * D);
        }

        float s[CHUNK];
#pragma unroll
        for (int j = 0; j < CHUNK; ++j) {
            float p = q4.x * v[j].x + q4.y * v[j].y + q4.z * v[j].z + q4.w * v[j].w;
#pragma unroll
            for (int off = 32; off >= 1; off >>= 1)
                p += __shfl_xor(p, off, 64);
            s[j] = p * 0.0625f;   // 1/sqrt(256)
        }

        float mnew = m_run;
#pragma unroll
        for (int j = 0; j < CHUNK; ++j) mnew = fmaxf(mnew, s[j]);
        const float alpha = __expf(m_run - mnew);   // first iter: exp(-inf)=0 zeroes o4/l_run
        float pj[CHUNK];
        float psum = 0.f;
#pragma unroll
        for (int j = 0; j < CHUNK; ++j) { pj[j] = __expf(s[j] - mnew); psum += pj[j]; }
        l_run = l_run * alpha + psum;
        o4.x *= alpha; o4.y *= alpha; o4.z *= alpha; o4.w *= alpha;
#pragma unroll
        for (int j = 0; j < CHUNK; ++j) {
            o4.x += pj[j] * v[j].x;
            o4.y += pj[j] * v[j].y;
            o4.z += pj[j] * v[j].z;
            o4.w += pj[j] * v[j].w;
        }
        m_run = mnew;

        if (more) {
#pragma unroll
            for (int j = 0; j < CHUNK; ++j) v[j] = vn[j];
        }
    }

    // combine 16 per-wave partials through LDS -> one unnormalized block partial
    __shared__ float s_o[WAVES][D];
    __shared__ float s_m[WAVES];
    __shared__ float s_l[WAVES];

    *reinterpret_cast<float4*>(&s_o[wave][lane * 4]) = o4;
    if (lane == 0) { s_m[wave] = m_run; s_l[wave] = l_run; }
    __syncthreads();

    if (tid < D) {
        float M = -INFINITY;
#pragma unroll
        for (int w = 0; w < WAVES; ++w) M = fmaxf(M, s_m[w]);
        float L = 0.f, acc = 0.f;
#pragma unroll
        for (int w = 0; w < WAVES; ++w) {
            const float e = __expf(s_m[w] - M);
            L   += s_l[w] * e;
            acc += s_o[w][tid] * e;
        }
        float* wsp = ws + (size_t)blockIdx.x * WS_STRIDE;
        wsp[tid] = acc;
        if (tid == 0) { wsp[D] = M; wsp[D + 1] = L; }
    }
}

__global__ __launch_bounds__(D, 1)
void attn_q0_combine(const float* __restrict__ ws, float* __restrict__ out) {
    const int b = blockIdx.x;
    const int d = threadIdx.x;
    const float* p0 = ws + (size_t)(b * 2 + 0) * WS_STRIDE;
    const float* p1 = ws + (size_t)(b * 2 + 1) * WS_STRIDE;
    const float m0 = p0[D], l0 = p0[D + 1];
    const float m1 = p1[D], l1 = p1[D + 1];
    const float M  = fmaxf(m0, m1);
    const float e0 = __expf(m0 - M), e1 = __expf(m1 - M);
    out[(size_t)b * D + d] = (e0 * p0[d] + e1 * p1[d]) / (e0 * l0 + e1 * l1);
}

extern "C" void kernel_launch(void* const* d_in, const int* in_sizes, int n_in,
                              void* d_out, int out_size, void* d_ws, size_t ws_size,
                              hipStream_t stream) {
    const float* x = (const float*)d_in[0];
    float* ws  = (float*)d_ws;
    float* out = (float*)d_out;
    attn_q0_partial<<<BATCH * SPLIT, THREADS, 0, stream>>>(x, ws);
    attn_q0_combine<<<BATCH, D, 0, stream>>>(ws, out);
}

// Round 3
// 44.068 us; speedup vs baseline: 2.0286x; 2.0286x over previous
//
#include <hip/hip_runtime.h>
#include <math.h>

// x: (B=256, N=1024, D=256) fp32.  out = softmax(x[b,0,:] @ x[b]^T / 16) @ x[b] -> (256,1,256)
// R3: identical to the 48.1us R1 kernel EXCEPT the key->wave mapping.
// Per chunk-round c the block reads one contiguous 64-key (64KB) window:
// wave w owns rows c*64 + w*4 .. +3. One advancing DRAM frontier per CU
// instead of 16 interleaved streams.
constexpr int BATCH = 256;
constexpr int N = 1024;
constexpr int D = 256;
constexpr int WAVES = 16;                        // 1024 threads / 64
constexpr int THREADS = WAVES * 64;
constexpr int CHUNK = 4;
constexpr int ROUND_KEYS = WAVES * CHUNK;        // 64 keys per block per round
constexpr int NCHUNK = N / ROUND_KEYS;           // 16 rounds

__global__ __launch_bounds__(THREADS, 1)
void attn_q0_kernel(const float* __restrict__ x, float* __restrict__ out) {
    const int b    = blockIdx.x;
    const int tid  = threadIdx.x;
    const int wave = tid >> 6;
    const int lane = tid & 63;

    const float* __restrict__ xb = x + (size_t)b * (N * D);

    // q fragment: lane i holds q[4i..4i+3] (row 0; L1-broadcast across waves)
    const float4 q4 = *reinterpret_cast<const float4*>(xb + lane * 4);

    // row pointer for (chunk c, j): rows c*64 + wave*4 + j  -> contiguous 4KB per wave
    const float* __restrict__ wbase = xb + (size_t)(wave * CHUNK) * D + lane * 4;

    float  m_run = -INFINITY;
    float  l_run = 0.f;
    float4 o4    = make_float4(0.f, 0.f, 0.f, 0.f);

    float4 v[CHUNK];
#pragma unroll
    for (int j = 0; j < CHUNK; ++j)
        v[j] = *reinterpret_cast<const float4*>(wbase + j * D);

    for (int c = 0; c < NCHUNK; ++c) {
        // prefetch next round's contiguous window
        float4 vn[CHUNK];
        const bool more = (c + 1 < NCHUNK);
        if (more) {
            const float* nb = wbase + (size_t)(c + 1) * ROUND_KEYS * D;
#pragma unroll
            for (int j = 0; j < CHUNK; ++j)
                vn[j] = *reinterpret_cast<const float4*>(nb + j * D);
        }

        // scores for the 4 keys (independent butterfly reduces -> ILP)
        float s[CHUNK];
#pragma unroll
        for (int j = 0; j < CHUNK; ++j) {
            float p = q4.x * v[j].x + q4.y * v[j].y + q4.z * v[j].z + q4.w * v[j].w;
#pragma unroll
            for (int off = 32; off >= 1; off >>= 1)
                p += __shfl_xor(p, off, 64);
            s[j] = p * 0.0625f;   // 1/sqrt(256)
        }

        // online softmax update, one rescale per 4 keys
        float mnew = m_run;
#pragma unroll
        for (int j = 0; j < CHUNK; ++j) mnew = fmaxf(mnew, s[j]);
        const float alpha = __expf(m_run - mnew);  // first round: exp(-inf)=0 zeroes o4/l_run
        float pj[CHUNK];
        float psum = 0.f;
#pragma unroll
        for (int j = 0; j < CHUNK; ++j) { pj[j] = __expf(s[j] - mnew); psum += pj[j]; }
        l_run = l_run * alpha + psum;
        o4.x *= alpha; o4.y *= alpha; o4.z *= alpha; o4.w *= alpha;
#pragma unroll
        for (int j = 0; j < CHUNK; ++j) {
            o4.x += pj[j] * v[j].x;
            o4.y += pj[j] * v[j].y;
            o4.z += pj[j] * v[j].z;
            o4.w += pj[j] * v[j].w;
        }
        m_run = mnew;

        if (more) {
#pragma unroll
            for (int j = 0; j < CHUNK; ++j) v[j] = vn[j];
        }
    }

    // combine 16 per-wave partials through LDS
    __shared__ float s_o[WAVES][D];
    __shared__ float s_m[WAVES];
    __shared__ float s_l[WAVES];

    *reinterpret_cast<float4*>(&s_o[wave][lane * 4]) = o4;
    if (lane == 0) { s_m[wave] = m_run; s_l[wave] = l_run; }
    __syncthreads();

    if (tid < D) {
        float M = -INFINITY;
#pragma unroll
        for (int w = 0; w < WAVES; ++w) M = fmaxf(M, s_m[w]);
        float L = 0.f, acc = 0.f;
#pragma unroll
        for (int w = 0; w < WAVES; ++w) {
            const float e = __expf(s_m[w] - M);
            L   += s_l[w] * e;
            acc += s_o[w][tid] * e;
        }
        out[(size_t)b * D + tid] = acc / L;
    }
}

extern "C" void kernel_launch(void* const* d_in, const int* in_sizes, int n_in,
                              void* d_out, int out_size, void* d_ws, size_t ws_size,
                              hipStream_t stream) {
    const float* x = (const float*)d_in[0];
    float* out = (float*)d_out;
    attn_q0_kernel<<<BATCH, THREADS, 0, stream>>>(x, out);
}